// Round 1
// baseline (837.420 us; speedup 1.0000x reference)
//
#include <hip/hip_runtime.h>

#define N_NODES 100000
#define IN_C 32
#define HID_C 64
#define OUT_C 5
#define N_EDGES 1600000

// ---------------------------------------------------------------------------
// Scatter layer 1: agg1[dst] += x[src]  (per (edge, channel) thread), and
// deg[dst] += 1 (once per edge, from channel-0 lane).
// ---------------------------------------------------------------------------
__global__ __launch_bounds__(256) void scatter1_kernel(
    const float* __restrict__ x,
    const int* __restrict__ src,
    const int* __restrict__ dst,
    float* __restrict__ agg,
    float* __restrict__ deg) {
  long long t = (long long)blockIdx.x * blockDim.x + threadIdx.x;
  const long long total = (long long)N_EDGES * IN_C;
  if (t >= total) return;
  int e = (int)(t >> 5);  // / IN_C
  int c = (int)(t & (IN_C - 1));
  int s = src[e];
  int d = dst[e];
  atomicAdd(&agg[(long long)d * IN_C + c], x[(long long)s * IN_C + c]);
  if (c == 0) atomicAdd(&deg[d], 1.0f);
}

// ---------------------------------------------------------------------------
// Scatter layer 2: agg2[dst] += h1[src]  (per (edge, channel) thread).
// ---------------------------------------------------------------------------
__global__ __launch_bounds__(256) void scatter2_kernel(
    const float* __restrict__ h,
    const int* __restrict__ src,
    const int* __restrict__ dst,
    float* __restrict__ agg) {
  long long t = (long long)blockIdx.x * blockDim.x + threadIdx.x;
  const long long total = (long long)N_EDGES * HID_C;
  if (t >= total) return;
  int e = (int)(t >> 6);  // / HID_C
  int c = (int)(t & (HID_C - 1));
  int s = src[e];
  int d = dst[e];
  atomicAdd(&agg[(long long)d * HID_C + c], h[(long long)s * HID_C + c]);
}

// ---------------------------------------------------------------------------
// Layer 1 dense: h1 = relu( (agg1/deg) @ W1l^T + b1 + x @ W1r^T )
// One thread per (node, out_channel). Weights in LDS, padded +1 to kill the
// "64 lanes -> 1 bank" conflict of W[o*32+c].
// ---------------------------------------------------------------------------
__global__ __launch_bounds__(256) void layer1_kernel(
    const float* __restrict__ x,
    const float* __restrict__ agg,
    const float* __restrict__ deg,
    const float* __restrict__ Wl,   // [HID_C, IN_C]
    const float* __restrict__ bl,   // [HID_C]
    const float* __restrict__ Wr,   // [HID_C, IN_C]
    float* __restrict__ h) {
  __shared__ float sWl[HID_C * (IN_C + 1)];
  __shared__ float sWr[HID_C * (IN_C + 1)];
  __shared__ float sb[HID_C];
  for (int i = threadIdx.x; i < HID_C * IN_C; i += blockDim.x) {
    int o = i / IN_C, c = i - o * IN_C;
    sWl[o * (IN_C + 1) + c] = Wl[i];
    sWr[o * (IN_C + 1) + c] = Wr[i];
  }
  if (threadIdx.x < HID_C) sb[threadIdx.x] = bl[threadIdx.x];
  __syncthreads();

  long long t = (long long)blockIdx.x * blockDim.x + threadIdx.x;
  if (t >= (long long)N_NODES * HID_C) return;
  int node = (int)(t >> 6);
  int o = (int)(t & (HID_C - 1));
  float inv = 1.0f / fmaxf(deg[node], 1.0f);
  const float* xr = &x[(long long)node * IN_C];
  const float* ar = &agg[(long long)node * IN_C];
  float acc = sb[o];
  const float* wl = &sWl[o * (IN_C + 1)];
  const float* wr = &sWr[o * (IN_C + 1)];
#pragma unroll
  for (int c = 0; c < IN_C; ++c) {
    acc += (ar[c] * inv) * wl[c] + xr[c] * wr[c];
  }
  h[t] = fmaxf(acc, 0.0f);
}

// ---------------------------------------------------------------------------
// Layer 2 dense: h2 = relu( (agg2/deg) @ W2l^T + b2 + h1 @ W2r^T )
// ---------------------------------------------------------------------------
__global__ __launch_bounds__(256) void layer2_kernel(
    const float* __restrict__ hin,
    const float* __restrict__ agg,
    const float* __restrict__ deg,
    const float* __restrict__ Wl,   // [HID_C, HID_C]
    const float* __restrict__ bl,
    const float* __restrict__ Wr,   // [HID_C, HID_C]
    float* __restrict__ hout) {
  __shared__ float sWl[HID_C * (HID_C + 1)];
  __shared__ float sWr[HID_C * (HID_C + 1)];
  __shared__ float sb[HID_C];
  for (int i = threadIdx.x; i < HID_C * HID_C; i += blockDim.x) {
    int o = i / HID_C, c = i - o * HID_C;
    sWl[o * (HID_C + 1) + c] = Wl[i];
    sWr[o * (HID_C + 1) + c] = Wr[i];
  }
  if (threadIdx.x < HID_C) sb[threadIdx.x] = bl[threadIdx.x];
  __syncthreads();

  long long t = (long long)blockIdx.x * blockDim.x + threadIdx.x;
  if (t >= (long long)N_NODES * HID_C) return;
  int node = (int)(t >> 6);
  int o = (int)(t & (HID_C - 1));
  float inv = 1.0f / fmaxf(deg[node], 1.0f);
  const float* xr = &hin[(long long)node * HID_C];
  const float* ar = &agg[(long long)node * HID_C];
  float acc = sb[o];
  const float* wl = &sWl[o * (HID_C + 1)];
  const float* wr = &sWr[o * (HID_C + 1)];
#pragma unroll
  for (int c = 0; c < HID_C; ++c) {
    acc += (ar[c] * inv) * wl[c] + xr[c] * wr[c];
  }
  hout[t] = fmaxf(acc, 0.0f);
}

// ---------------------------------------------------------------------------
// Head: out = h2 @ Wlin^T + blin    ([N,64] x [5,64]^T -> [N,5])
// One thread per node (5 outputs each).
// ---------------------------------------------------------------------------
__global__ __launch_bounds__(256) void head_kernel(
    const float* __restrict__ h,
    const float* __restrict__ W,   // [OUT_C, HID_C]
    const float* __restrict__ b,   // [OUT_C]
    float* __restrict__ out) {
  int t = blockIdx.x * blockDim.x + threadIdx.x;
  if (t >= N_NODES) return;
  float acc[OUT_C];
#pragma unroll
  for (int j = 0; j < OUT_C; ++j) acc[j] = b[j];
  const float* hr = &h[(long long)t * HID_C];
#pragma unroll 8
  for (int c = 0; c < HID_C; ++c) {
    float v = hr[c];
#pragma unroll
    for (int j = 0; j < OUT_C; ++j) acc[j] += v * W[j * HID_C + c];
  }
#pragma unroll
  for (int j = 0; j < OUT_C; ++j) out[(long long)t * OUT_C + j] = acc[j];
}

extern "C" void kernel_launch(void* const* d_in, const int* in_sizes, int n_in,
                              void* d_out, int out_size, void* d_ws, size_t ws_size,
                              hipStream_t stream) {
  const float* x    = (const float*)d_in[0];
  const int*   ei   = (const int*)d_in[1];       // [2, E] int32
  const float* W1l  = (const float*)d_in[2];
  const float* b1   = (const float*)d_in[3];
  const float* W1r  = (const float*)d_in[4];
  const float* W2l  = (const float*)d_in[5];
  const float* b2   = (const float*)d_in[6];
  const float* W2r  = (const float*)d_in[7];
  const float* Wlin = (const float*)d_in[8];
  const float* blin = (const float*)d_in[9];

  const int* src = ei;             // edge_index[0]
  const int* dst = ei + N_EDGES;   // edge_index[1]

  // Workspace layout (floats):
  //   deg  [N]          0.4 MB
  //   agg1 [N*32]      12.8 MB
  //   h1   [N*64]      25.6 MB
  //   agg2 [N*64]      25.6 MB
  //   h2   [N*64]      25.6 MB
  float* deg  = (float*)d_ws;
  float* agg1 = deg + N_NODES;
  float* h1   = agg1 + (size_t)N_NODES * IN_C;
  float* agg2 = h1 + (size_t)N_NODES * HID_C;
  float* h2   = agg2 + (size_t)N_NODES * HID_C;

  hipMemsetAsync(deg, 0, (size_t)N_NODES * sizeof(float), stream);
  hipMemsetAsync(agg1, 0, (size_t)N_NODES * IN_C * sizeof(float), stream);
  hipMemsetAsync(agg2, 0, (size_t)N_NODES * HID_C * sizeof(float), stream);

  {
    long long total = (long long)N_EDGES * IN_C;
    int blocks = (int)((total + 255) / 256);
    scatter1_kernel<<<blocks, 256, 0, stream>>>(x, src, dst, agg1, deg);
  }
  {
    long long total = (long long)N_NODES * HID_C;
    int blocks = (int)((total + 255) / 256);
    layer1_kernel<<<blocks, 256, 0, stream>>>(x, agg1, deg, W1l, b1, W1r, h1);
  }
  {
    long long total = (long long)N_EDGES * HID_C;
    int blocks = (int)((total + 255) / 256);
    scatter2_kernel<<<blocks, 256, 0, stream>>>(h1, src, dst, agg2);
  }
  {
    long long total = (long long)N_NODES * HID_C;
    int blocks = (int)((total + 255) / 256);
    layer2_kernel<<<blocks, 256, 0, stream>>>(h1, agg2, deg, W2l, b2, W2r, h2);
  }
  {
    int blocks = (N_NODES + 255) / 256;
    head_kernel<<<blocks, 256, 0, stream>>>(h2, Wlin, blin, (float*)d_out);
  }
}

// Round 3
// 545.986 us; speedup vs baseline: 1.5338x; 1.5338x over previous
//
#include <hip/hip_runtime.h>

#define N_NODES 100000
#define IN_C 32
#define HID_C 64
#define OUT_C 5
#define N_EDGES 1600000
#define SCAN_BLK 1024
#define N_SCAN_BLKS ((N_NODES + SCAN_BLK - 1) / SCAN_BLK)   // 98

// ---------------------------------------------------------------------------
// CSR build step 1: histogram of dst. cnt[] must be zeroed before.
// ---------------------------------------------------------------------------
__global__ __launch_bounds__(256) void deg_count_kernel(
    const int* __restrict__ dst, int* __restrict__ cnt) {
  int e = blockIdx.x * blockDim.x + threadIdx.x;
  if (e >= N_EDGES) return;
  atomicAdd(&cnt[dst[e]], 1);
}

// ---------------------------------------------------------------------------
// CSR build step 2a: per-block inclusive scan of cnt -> rowptr[i+1] (local),
// block totals -> partial[b].
// ---------------------------------------------------------------------------
__global__ __launch_bounds__(SCAN_BLK) void scan1_kernel(
    const int* __restrict__ cnt, int* __restrict__ rowptr,
    int* __restrict__ partial) {
  __shared__ int s[SCAN_BLK];
  int t = threadIdx.x;
  int g = blockIdx.x * SCAN_BLK + t;
  int v = (g < N_NODES) ? cnt[g] : 0;
  s[t] = v;
  __syncthreads();
#pragma unroll
  for (int off = 1; off < SCAN_BLK; off <<= 1) {
    int u = (t >= off) ? s[t - off] : 0;
    __syncthreads();
    s[t] += u;
    __syncthreads();
  }
  if (g < N_NODES) rowptr[g + 1] = s[t];
  if (t == SCAN_BLK - 1) partial[blockIdx.x] = s[t];
}

// ---------------------------------------------------------------------------
// CSR build step 2b: exclusive scan of the 98 block totals (single block).
// ---------------------------------------------------------------------------
__global__ __launch_bounds__(128) void scan2_kernel(int* __restrict__ partial) {
  __shared__ int s[128];
  int t = threadIdx.x;
  int v = (t < N_SCAN_BLKS) ? partial[t] : 0;
  s[t] = v;
  __syncthreads();
#pragma unroll
  for (int off = 1; off < 128; off <<= 1) {
    int u = (t >= off) ? s[t - off] : 0;
    __syncthreads();
    s[t] += u;
    __syncthreads();
  }
  if (t < N_SCAN_BLKS) partial[t] = s[t] - v;  // exclusive
}

// ---------------------------------------------------------------------------
// CSR build step 2c: add block offsets; also seed cursor[] = rowptr[].
// ---------------------------------------------------------------------------
__global__ __launch_bounds__(256) void scan3_kernel(
    int* __restrict__ rowptr, const int* __restrict__ partial,
    int* __restrict__ cursor) {
  int i = blockIdx.x * blockDim.x + threadIdx.x;
  if (i >= N_NODES) return;
  int val = rowptr[i + 1] + partial[i >> 10];
  rowptr[i + 1] = val;
  if (i + 1 < N_NODES) cursor[i + 1] = val;
  if (i == 0) { rowptr[0] = 0; cursor[0] = 0; }
}

// ---------------------------------------------------------------------------
// CSR build step 3: fill csr_src (src node per slot, grouped by dst).
// ---------------------------------------------------------------------------
__global__ __launch_bounds__(256) void fill_kernel(
    const int* __restrict__ src, const int* __restrict__ dst,
    int* __restrict__ cursor, int* __restrict__ csr_src) {
  int e = blockIdx.x * blockDim.x + threadIdx.x;
  if (e >= N_EDGES) return;
  int d = dst[e];
  int pos = atomicAdd(&cursor[d], 1);
  csr_src[pos] = src[e];
}

// ---------------------------------------------------------------------------
// Mean aggregation layer 1: mean1[n] = (1/deg) * sum_{s in adj(n)} x[s]
// Thread = (node, float4-chunk). 8 chunks of 4 = 32 channels. No atomics.
// ---------------------------------------------------------------------------
__global__ __launch_bounds__(256) void agg_mean1_kernel(
    const float* __restrict__ x, const int* __restrict__ rowptr,
    const int* __restrict__ csr, float* __restrict__ mean) {
  int t = blockIdx.x * blockDim.x + threadIdx.x;
  if (t >= N_NODES * (IN_C / 4)) return;
  int node = t >> 3;
  int q = t & 7;
  int p0 = rowptr[node], p1 = rowptr[node + 1];
  const float4* x4 = (const float4*)x;
  float4 acc = make_float4(0.f, 0.f, 0.f, 0.f);
  int k = p0;
  for (; k + 4 <= p1; k += 4) {
    int s0 = csr[k], s1 = csr[k + 1], s2 = csr[k + 2], s3 = csr[k + 3];
    float4 a = x4[s0 * 8 + q];
    float4 b = x4[s1 * 8 + q];
    float4 c = x4[s2 * 8 + q];
    float4 d = x4[s3 * 8 + q];
    acc.x += a.x + b.x + c.x + d.x;
    acc.y += a.y + b.y + c.y + d.y;
    acc.z += a.z + b.z + c.z + d.z;
    acc.w += a.w + b.w + c.w + d.w;
  }
  for (; k < p1; ++k) {
    float4 a = x4[csr[k] * 8 + q];
    acc.x += a.x; acc.y += a.y; acc.z += a.z; acc.w += a.w;
  }
  float inv = 1.0f / fmaxf((float)(p1 - p0), 1.0f);
  acc.x *= inv; acc.y *= inv; acc.z *= inv; acc.w *= inv;
  ((float4*)mean)[t] = acc;
}

// ---------------------------------------------------------------------------
// Mean aggregation layer 2: 16 float4 chunks = 64 channels.
// ---------------------------------------------------------------------------
__global__ __launch_bounds__(256) void agg_mean2_kernel(
    const float* __restrict__ h, const int* __restrict__ rowptr,
    const int* __restrict__ csr, float* __restrict__ mean) {
  int t = blockIdx.x * blockDim.x + threadIdx.x;
  if (t >= N_NODES * (HID_C / 4)) return;
  int node = t >> 4;
  int q = t & 15;
  int p0 = rowptr[node], p1 = rowptr[node + 1];
  const float4* h4 = (const float4*)h;
  float4 acc = make_float4(0.f, 0.f, 0.f, 0.f);
  int k = p0;
  for (; k + 4 <= p1; k += 4) {
    int s0 = csr[k], s1 = csr[k + 1], s2 = csr[k + 2], s3 = csr[k + 3];
    float4 a = h4[s0 * 16 + q];
    float4 b = h4[s1 * 16 + q];
    float4 c = h4[s2 * 16 + q];
    float4 d = h4[s3 * 16 + q];
    acc.x += a.x + b.x + c.x + d.x;
    acc.y += a.y + b.y + c.y + d.y;
    acc.z += a.z + b.z + c.z + d.z;
    acc.w += a.w + b.w + c.w + d.w;
  }
  for (; k < p1; ++k) {
    float4 a = h4[csr[k] * 16 + q];
    acc.x += a.x; acc.y += a.y; acc.z += a.z; acc.w += a.w;
  }
  float inv = 1.0f / fmaxf((float)(p1 - p0), 1.0f);
  acc.x *= inv; acc.y *= inv; acc.z *= inv; acc.w *= inv;
  ((float4*)mean)[t] = acc;
}

// ---------------------------------------------------------------------------
// Layer 1 dense: h1 = relu( mean1 @ W1l^T + b1 + x @ W1r^T )
// ---------------------------------------------------------------------------
__global__ __launch_bounds__(256) void layer1_kernel(
    const float* __restrict__ x, const float* __restrict__ mean,
    const float* __restrict__ Wl, const float* __restrict__ bl,
    const float* __restrict__ Wr, float* __restrict__ h) {
  __shared__ float sWl[HID_C * (IN_C + 1)];
  __shared__ float sWr[HID_C * (IN_C + 1)];
  __shared__ float sb[HID_C];
  for (int i = threadIdx.x; i < HID_C * IN_C; i += blockDim.x) {
    int o = i / IN_C, c = i - o * IN_C;
    sWl[o * (IN_C + 1) + c] = Wl[i];
    sWr[o * (IN_C + 1) + c] = Wr[i];
  }
  if (threadIdx.x < HID_C) sb[threadIdx.x] = bl[threadIdx.x];
  __syncthreads();

  int t = blockIdx.x * blockDim.x + threadIdx.x;
  if (t >= N_NODES * HID_C) return;
  int node = t >> 6;
  int o = t & (HID_C - 1);
  const float* xr = &x[(size_t)node * IN_C];
  const float* ar = &mean[(size_t)node * IN_C];
  float acc = sb[o];
  const float* wl = &sWl[o * (IN_C + 1)];
  const float* wr = &sWr[o * (IN_C + 1)];
#pragma unroll
  for (int c = 0; c < IN_C; ++c) {
    acc += ar[c] * wl[c] + xr[c] * wr[c];
  }
  h[t] = fmaxf(acc, 0.0f);
}

// ---------------------------------------------------------------------------
// Layer 2 dense: h2 = relu( mean2 @ W2l^T + b2 + h1 @ W2r^T )
// ---------------------------------------------------------------------------
__global__ __launch_bounds__(256) void layer2_kernel(
    const float* __restrict__ hin, const float* __restrict__ mean,
    const float* __restrict__ Wl, const float* __restrict__ bl,
    const float* __restrict__ Wr, float* __restrict__ hout) {
  __shared__ float sWl[HID_C * (HID_C + 1)];
  __shared__ float sWr[HID_C * (HID_C + 1)];
  __shared__ float sb[HID_C];
  for (int i = threadIdx.x; i < HID_C * HID_C; i += blockDim.x) {
    int o = i / HID_C, c = i - o * HID_C;
    sWl[o * (HID_C + 1) + c] = Wl[i];
    sWr[o * (HID_C + 1) + c] = Wr[i];
  }
  if (threadIdx.x < HID_C) sb[threadIdx.x] = bl[threadIdx.x];
  __syncthreads();

  int t = blockIdx.x * blockDim.x + threadIdx.x;
  if (t >= N_NODES * HID_C) return;
  int node = t >> 6;
  int o = t & (HID_C - 1);
  const float* xr = &hin[(size_t)node * HID_C];
  const float* ar = &mean[(size_t)node * HID_C];
  float acc = sb[o];
  const float* wl = &sWl[o * (HID_C + 1)];
  const float* wr = &sWr[o * (HID_C + 1)];
#pragma unroll
  for (int c = 0; c < HID_C; ++c) {
    acc += ar[c] * wl[c] + xr[c] * wr[c];
  }
  hout[t] = fmaxf(acc, 0.0f);
}

// ---------------------------------------------------------------------------
// Head: out = h2 @ Wlin^T + blin
// ---------------------------------------------------------------------------
__global__ __launch_bounds__(256) void head_kernel(
    const float* __restrict__ h, const float* __restrict__ W,
    const float* __restrict__ b, float* __restrict__ out) {
  int t = blockIdx.x * blockDim.x + threadIdx.x;
  if (t >= N_NODES) return;
  float acc[OUT_C];
#pragma unroll
  for (int j = 0; j < OUT_C; ++j) acc[j] = b[j];
  const float* hr = &h[(size_t)t * HID_C];
#pragma unroll 8
  for (int c = 0; c < HID_C; ++c) {
    float v = hr[c];
#pragma unroll
    for (int j = 0; j < OUT_C; ++j) acc[j] += v * W[j * HID_C + c];
  }
#pragma unroll
  for (int j = 0; j < OUT_C; ++j) out[(size_t)t * OUT_C + j] = acc[j];
}

extern "C" void kernel_launch(void* const* d_in, const int* in_sizes, int n_in,
                              void* d_out, int out_size, void* d_ws, size_t ws_size,
                              hipStream_t stream) {
  const float* x    = (const float*)d_in[0];
  const int*   ei   = (const int*)d_in[1];
  const float* W1l  = (const float*)d_in[2];
  const float* b1   = (const float*)d_in[3];
  const float* W1r  = (const float*)d_in[4];
  const float* W2l  = (const float*)d_in[5];
  const float* b2   = (const float*)d_in[6];
  const float* W2r  = (const float*)d_in[7];
  const float* Wlin = (const float*)d_in[8];
  const float* blin = (const float*)d_in[9];

  const int* src = ei;
  const int* dst = ei + N_EDGES;

  // Workspace layout (4B units):
  //   rowptr  [N+1]  (+pad to 100004)
  //   cursor  [N]    (doubles as the histogram cnt)
  //   partial [128]
  //   csr_src [E]
  //   mean    [N*64]  (mean1 uses first N*32, then reused for mean2)
  //   h1      [N*64]
  //   h2      [N*64]
  int* rowptr  = (int*)d_ws;
  int* cursor  = rowptr + 100004;
  int* partial = cursor + N_NODES;
  int* csr_src = partial + 128;
  float* mean  = (float*)(csr_src + N_EDGES);
  float* h1    = mean + (size_t)N_NODES * HID_C;
  float* h2    = h1 + (size_t)N_NODES * HID_C;

  hipMemsetAsync(cursor, 0, (size_t)N_NODES * sizeof(int), stream);

  const int EB = (N_EDGES + 255) / 256;
  deg_count_kernel<<<EB, 256, 0, stream>>>(dst, cursor);
  scan1_kernel<<<N_SCAN_BLKS, SCAN_BLK, 0, stream>>>(cursor, rowptr, partial);
  scan2_kernel<<<1, 128, 0, stream>>>(partial);
  scan3_kernel<<<(N_NODES + 255) / 256, 256, 0, stream>>>(rowptr, partial, cursor);
  fill_kernel<<<EB, 256, 0, stream>>>(src, dst, cursor, csr_src);

  agg_mean1_kernel<<<(N_NODES * (IN_C / 4) + 255) / 256, 256, 0, stream>>>(
      x, rowptr, csr_src, mean);
  layer1_kernel<<<(N_NODES * HID_C + 255) / 256, 256, 0, stream>>>(
      x, mean, W1l, b1, W1r, h1);
  agg_mean2_kernel<<<(N_NODES * (HID_C / 4) + 255) / 256, 256, 0, stream>>>(
      h1, rowptr, csr_src, mean);
  layer2_kernel<<<(N_NODES * HID_C + 255) / 256, 256, 0, stream>>>(
      h1, mean, W2l, b2, W2r, h2);
  head_kernel<<<(N_NODES + 255) / 256, 256, 0, stream>>>(
      h2, Wlin, blin, (float*)d_out);
}

// Round 8
// 375.744 us; speedup vs baseline: 2.2287x; 1.4531x over previous
//
#include <hip/hip_runtime.h>

#define N_NODES 100000
#define IN_C 32
#define HID_C 64
#define OUT_C 5
#define N_EDGES 1600000
#define SCAN_BLK 1024
#define N_SCAN_BLKS ((N_NODES + SCAN_BLK - 1) / SCAN_BLK)   // 98
#define N_TILES ((N_NODES + 63) / 64)                        // 1563

// ---------------------------------------------------------------------------
// CSR build step 1: histogram of dst. cnt[] must be zeroed before.
// ---------------------------------------------------------------------------
__global__ __launch_bounds__(256) void deg_count_kernel(
    const int* __restrict__ dst, int* __restrict__ cnt) {
  int e = blockIdx.x * blockDim.x + threadIdx.x;
  if (e >= N_EDGES) return;
  atomicAdd(&cnt[dst[e]], 1);
}

// ---------------------------------------------------------------------------
// CSR build step 2a: per-block inclusive scan of cnt.
// ---------------------------------------------------------------------------
__global__ __launch_bounds__(SCAN_BLK) void scan1_kernel(
    const int* __restrict__ cnt, int* __restrict__ rowptr,
    int* __restrict__ partial) {
  __shared__ int s[SCAN_BLK];
  int t = threadIdx.x;
  int g = blockIdx.x * SCAN_BLK + t;
  int v = (g < N_NODES) ? cnt[g] : 0;
  s[t] = v;
  __syncthreads();
#pragma unroll
  for (int off = 1; off < SCAN_BLK; off <<= 1) {
    int u = (t >= off) ? s[t - off] : 0;
    __syncthreads();
    s[t] += u;
    __syncthreads();
  }
  if (g < N_NODES) rowptr[g + 1] = s[t];
  if (t == SCAN_BLK - 1) partial[blockIdx.x] = s[t];
}

// ---------------------------------------------------------------------------
// CSR build step 2b: exclusive scan of block totals (single block).
// ---------------------------------------------------------------------------
__global__ __launch_bounds__(128) void scan2_kernel(int* __restrict__ partial) {
  __shared__ int s[128];
  int t = threadIdx.x;
  int v = (t < N_SCAN_BLKS) ? partial[t] : 0;
  s[t] = v;
  __syncthreads();
#pragma unroll
  for (int off = 1; off < 128; off <<= 1) {
    int u = (t >= off) ? s[t - off] : 0;
    __syncthreads();
    s[t] += u;
    __syncthreads();
  }
  if (t < N_SCAN_BLKS) partial[t] = s[t] - v;  // exclusive
}

// ---------------------------------------------------------------------------
// CSR build step 2c: add block offsets; seed cursor[] = rowptr[].
// ---------------------------------------------------------------------------
__global__ __launch_bounds__(256) void scan3_kernel(
    int* __restrict__ rowptr, const int* __restrict__ partial,
    int* __restrict__ cursor) {
  int i = blockIdx.x * blockDim.x + threadIdx.x;
  if (i >= N_NODES) return;
  int val = rowptr[i + 1] + partial[i >> 10];
  rowptr[i + 1] = val;
  if (i + 1 < N_NODES) cursor[i + 1] = val;
  if (i == 0) { rowptr[0] = 0; cursor[0] = 0; }
}

// ---------------------------------------------------------------------------
// CSR build step 3: fill csr_src.
// ---------------------------------------------------------------------------
__global__ __launch_bounds__(256) void fill_kernel(
    const int* __restrict__ src, const int* __restrict__ dst,
    int* __restrict__ cursor, int* __restrict__ csr_src) {
  int e = blockIdx.x * blockDim.x + threadIdx.x;
  if (e >= N_EDGES) return;
  int d = dst[e];
  int pos = atomicAdd(&cursor[d], 1);
  csr_src[pos] = src[e];
}

// ---------------------------------------------------------------------------
// Mean aggregation layer 1 (gather, no atomics).
// ---------------------------------------------------------------------------
__global__ __launch_bounds__(256) void agg_mean1_kernel(
    const float* __restrict__ x, const int* __restrict__ rowptr,
    const int* __restrict__ csr, float* __restrict__ mean) {
  int t = blockIdx.x * blockDim.x + threadIdx.x;
  if (t >= N_NODES * (IN_C / 4)) return;
  int node = t >> 3;
  int q = t & 7;
  int p0 = rowptr[node], p1 = rowptr[node + 1];
  const float4* x4 = (const float4*)x;
  float4 acc = make_float4(0.f, 0.f, 0.f, 0.f);
  int k = p0;
  for (; k + 4 <= p1; k += 4) {
    int s0 = csr[k], s1 = csr[k + 1], s2 = csr[k + 2], s3 = csr[k + 3];
    float4 a = x4[s0 * 8 + q];
    float4 b = x4[s1 * 8 + q];
    float4 c = x4[s2 * 8 + q];
    float4 d = x4[s3 * 8 + q];
    acc.x += a.x + b.x + c.x + d.x;
    acc.y += a.y + b.y + c.y + d.y;
    acc.z += a.z + b.z + c.z + d.z;
    acc.w += a.w + b.w + c.w + d.w;
  }
  for (; k < p1; ++k) {
    float4 a = x4[csr[k] * 8 + q];
    acc.x += a.x; acc.y += a.y; acc.z += a.z; acc.w += a.w;
  }
  float inv = 1.0f / fmaxf((float)(p1 - p0), 1.0f);
  acc.x *= inv; acc.y *= inv; acc.z *= inv; acc.w *= inv;
  ((float4*)mean)[t] = acc;
}

// ---------------------------------------------------------------------------
// Mean aggregation layer 2 (gather, no atomics).
// ---------------------------------------------------------------------------
__global__ __launch_bounds__(256) void agg_mean2_kernel(
    const float* __restrict__ h, const int* __restrict__ rowptr,
    const int* __restrict__ csr, float* __restrict__ mean) {
  int t = blockIdx.x * blockDim.x + threadIdx.x;
  if (t >= N_NODES * (HID_C / 4)) return;
  int node = t >> 4;
  int q = t & 15;
  int p0 = rowptr[node], p1 = rowptr[node + 1];
  const float4* h4 = (const float4*)h;
  float4 acc = make_float4(0.f, 0.f, 0.f, 0.f);
  int k = p0;
  for (; k + 4 <= p1; k += 4) {
    int s0 = csr[k], s1 = csr[k + 1], s2 = csr[k + 2], s3 = csr[k + 3];
    float4 a = h4[s0 * 16 + q];
    float4 b = h4[s1 * 16 + q];
    float4 c = h4[s2 * 16 + q];
    float4 d = h4[s3 * 16 + q];
    acc.x += a.x + b.x + c.x + d.x;
    acc.y += a.y + b.y + c.y + d.y;
    acc.z += a.z + b.z + c.z + d.z;
    acc.w += a.w + b.w + c.w + d.w;
  }
  for (; k < p1; ++k) {
    float4 a = h4[csr[k] * 16 + q];
    acc.x += a.x; acc.y += a.y; acc.z += a.z; acc.w += a.w;
  }
  float inv = 1.0f / fmaxf((float)(p1 - p0), 1.0f);
  acc.x *= inv; acc.y *= inv; acc.z *= inv; acc.w *= inv;
  ((float4*)mean)[t] = acc;
}

// ---------------------------------------------------------------------------
// Layer 1 as tiled GEMM: h1[64-node tile][64] = relu([mean1|x] @ [W1l;W1r]^T + b1)
// K = 64. Block: 256 threads = 16x16; thread computes 4 nodes x 4 outs.
// ---------------------------------------------------------------------------
__global__ __launch_bounds__(256) void layer1_gemm_kernel(
    const float* __restrict__ x, const float* __restrict__ mean,
    const float* __restrict__ Wl, const float* __restrict__ bl,
    const float* __restrict__ Wr, float* __restrict__ h1) {
  const int LD = 17;  // float4 row stride (16 data + 1 pad)
  __shared__ float4 sA[64 * LD];
  __shared__ float4 sB[64 * LD];
  __shared__ float sbias[64];
  int tid = threadIdx.x;
  int base = blockIdx.x * 64;
  const float4* mean4 = (const float4*)mean;
  const float4* x4 = (const float4*)x;
  const float4* Wl4 = (const float4*)Wl;
  const float4* Wr4 = (const float4*)Wr;
  const float4 zero = make_float4(0.f, 0.f, 0.f, 0.f);
  for (int idx = tid; idx < 64 * 16; idx += 256) {
    int row = idx >> 4, col = idx & 15;
    int node = base + row;
    float4 v = zero;
    if (node < N_NODES)
      v = (col < 8) ? mean4[node * 8 + col] : x4[node * 8 + (col - 8)];
    sA[row * LD + col] = v;
    sB[row * LD + col] = (col < 8) ? Wl4[row * 8 + col] : Wr4[row * 8 + (col - 8)];
  }
  if (tid < 64) sbias[tid] = bl[tid];
  __syncthreads();

  int tn = tid & 15;   // node group
  int to = tid >> 4;   // output group (0..15), outs to*4..to*4+3
  float acc[4][4];
#pragma unroll
  for (int i = 0; i < 4; ++i)
#pragma unroll
    for (int j = 0; j < 4; ++j) acc[i][j] = 0.f;

#pragma unroll 4
  for (int k4 = 0; k4 < 16; ++k4) {
    float4 a[4], b[4];
#pragma unroll
    for (int i = 0; i < 4; ++i) a[i] = sA[(tn + i * 16) * LD + k4];
#pragma unroll
    for (int j = 0; j < 4; ++j) b[j] = sB[(to * 4 + j) * LD + k4];
#pragma unroll
    for (int i = 0; i < 4; ++i)
#pragma unroll
      for (int j = 0; j < 4; ++j) {
        acc[i][j] = fmaf(a[i].x, b[j].x, acc[i][j]);
        acc[i][j] = fmaf(a[i].y, b[j].y, acc[i][j]);
        acc[i][j] = fmaf(a[i].z, b[j].z, acc[i][j]);
        acc[i][j] = fmaf(a[i].w, b[j].w, acc[i][j]);
      }
  }

  float4* h14 = (float4*)h1;
#pragma unroll
  for (int i = 0; i < 4; ++i) {
    int node = base + tn + i * 16;
    if (node < N_NODES) {
      float4 v;
      v.x = fmaxf(acc[i][0] + sbias[to * 4 + 0], 0.f);
      v.y = fmaxf(acc[i][1] + sbias[to * 4 + 1], 0.f);
      v.z = fmaxf(acc[i][2] + sbias[to * 4 + 2], 0.f);
      v.w = fmaxf(acc[i][3] + sbias[to * 4 + 3], 0.f);
      h14[node * 16 + to] = v;
    }
  }
}

// ---------------------------------------------------------------------------
// Layer 2 + head fused: h2 tile (64x64) computed as GEMM (K=128) into LDS,
// then out[node][5] = h2_row @ Wlin^T + blin. h2 never touches global.
// ---------------------------------------------------------------------------
__global__ __launch_bounds__(256) void layer2_head_kernel(
    const float* __restrict__ h1, const float* __restrict__ mean,
    const float* __restrict__ Wl, const float* __restrict__ bl,
    const float* __restrict__ Wr,
    const float* __restrict__ Wlin, const float* __restrict__ blin,
    float* __restrict__ out) {
  const int LD = 33;  // float4 row stride (32 data + 1 pad)
  __shared__ float4 sA[64 * LD];
  __shared__ float4 sB[64 * LD];
  __shared__ float sbias[64];
  __shared__ float sWlin[OUT_C * 64];
  __shared__ float sblin[OUT_C];
  int tid = threadIdx.x;
  int base = blockIdx.x * 64;
  const float4* mean4 = (const float4*)mean;
  const float4* h14 = (const float4*)h1;
  const float4* Wl4 = (const float4*)Wl;
  const float4* Wr4 = (const float4*)Wr;
  const float4 zero = make_float4(0.f, 0.f, 0.f, 0.f);
  for (int idx = tid; idx < 64 * 32; idx += 256) {
    int row = idx >> 5, col = idx & 31;
    int node = base + row;
    float4 v = zero;
    if (node < N_NODES)
      v = (col < 16) ? mean4[node * 16 + col] : h14[node * 16 + (col - 16)];
    sA[row * LD + col] = v;
    sB[row * LD + col] = (col < 16) ? Wl4[row * 16 + col] : Wr4[row * 16 + (col - 16)];
  }
  if (tid < 64) sbias[tid] = bl[tid];
  // FIX (R7): OUT_C*64 = 320 > 256 threads — must stride, not mask.
  for (int i = tid; i < OUT_C * 64; i += 256) sWlin[i] = Wlin[i];
  if (tid < OUT_C) sblin[tid] = blin[tid];
  __syncthreads();

  int tn = tid & 15;
  int to = tid >> 4;
  float acc[4][4];
#pragma unroll
  for (int i = 0; i < 4; ++i)
#pragma unroll
    for (int j = 0; j < 4; ++j) acc[i][j] = 0.f;

#pragma unroll 4
  for (int k4 = 0; k4 < 32; ++k4) {
    float4 a[4], b[4];
#pragma unroll
    for (int i = 0; i < 4; ++i) a[i] = sA[(tn + i * 16) * LD + k4];
#pragma unroll
    for (int j = 0; j < 4; ++j) b[j] = sB[(to * 4 + j) * LD + k4];
#pragma unroll
    for (int i = 0; i < 4; ++i)
#pragma unroll
      for (int j = 0; j < 4; ++j) {
        acc[i][j] = fmaf(a[i].x, b[j].x, acc[i][j]);
        acc[i][j] = fmaf(a[i].y, b[j].y, acc[i][j]);
        acc[i][j] = fmaf(a[i].z, b[j].z, acc[i][j]);
        acc[i][j] = fmaf(a[i].w, b[j].w, acc[i][j]);
      }
  }

  __syncthreads();  // everyone done reading sA -> reuse it for the h2 tile
  float* sH = (float*)sA;
  const int LDH = 69;  // gcd(69 mod 32, 32) = 1 -> conflict-free column walks
#pragma unroll
  for (int i = 0; i < 4; ++i) {
    int r = tn + i * 16;
#pragma unroll
    for (int j = 0; j < 4; ++j) {
      sH[r * LDH + to * 4 + j] = fmaxf(acc[i][j] + sbias[to * 4 + j], 0.f);
    }
  }
  __syncthreads();

  if (tid < 64) {
    int node = base + tid;
    if (node < N_NODES) {
      float o5[OUT_C];
#pragma unroll
      for (int m = 0; m < OUT_C; ++m) o5[m] = sblin[m];
      const float* hr = &sH[tid * LDH];
#pragma unroll 8
      for (int c = 0; c < HID_C; ++c) {
        float v = hr[c];
#pragma unroll
        for (int m = 0; m < OUT_C; ++m) o5[m] = fmaf(v, sWlin[m * 64 + c], o5[m]);
      }
#pragma unroll
      for (int m = 0; m < OUT_C; ++m) out[node * OUT_C + m] = o5[m];
    }
  }
}

extern "C" void kernel_launch(void* const* d_in, const int* in_sizes, int n_in,
                              void* d_out, int out_size, void* d_ws, size_t ws_size,
                              hipStream_t stream) {
  const float* x    = (const float*)d_in[0];
  const int*   ei   = (const int*)d_in[1];
  const float* W1l  = (const float*)d_in[2];
  const float* b1   = (const float*)d_in[3];
  const float* W1r  = (const float*)d_in[4];
  const float* W2l  = (const float*)d_in[5];
  const float* b2   = (const float*)d_in[6];
  const float* W2r  = (const float*)d_in[7];
  const float* Wlin = (const float*)d_in[8];
  const float* blin = (const float*)d_in[9];

  const int* src = ei;
  const int* dst = ei + N_EDGES;

  // Workspace layout (4B units):
  //   rowptr  [100004]
  //   cursor  [N]    (doubles as histogram)
  //   partial [128]
  //   csr_src [E]
  //   mean    [N*64] (mean1 in first N*32, reused for mean2)
  //   h1      [N*64]
  int* rowptr  = (int*)d_ws;
  int* cursor  = rowptr + 100004;
  int* partial = cursor + N_NODES;
  int* csr_src = partial + 128;
  float* mean  = (float*)(csr_src + N_EDGES);
  float* h1    = mean + (size_t)N_NODES * HID_C;

  hipMemsetAsync(cursor, 0, (size_t)N_NODES * sizeof(int), stream);

  const int EB = (N_EDGES + 255) / 256;
  deg_count_kernel<<<EB, 256, 0, stream>>>(dst, cursor);
  scan1_kernel<<<N_SCAN_BLKS, SCAN_BLK, 0, stream>>>(cursor, rowptr, partial);
  scan2_kernel<<<1, 128, 0, stream>>>(partial);
  scan3_kernel<<<(N_NODES + 255) / 256, 256, 0, stream>>>(rowptr, partial, cursor);
  fill_kernel<<<EB, 256, 0, stream>>>(src, dst, cursor, csr_src);

  agg_mean1_kernel<<<(N_NODES * (IN_C / 4) + 255) / 256, 256, 0, stream>>>(
      x, rowptr, csr_src, mean);
  layer1_gemm_kernel<<<N_TILES, 256, 0, stream>>>(
      x, mean, W1l, b1, W1r, h1);
  agg_mean2_kernel<<<(N_NODES * (HID_C / 4) + 255) / 256, 256, 0, stream>>>(
      h1, rowptr, csr_src, mean);
  layer2_head_kernel<<<N_TILES, 256, 0, stream>>>(
      h1, mean, W2l, b2, W2r, Wlin, blin, (float*)d_out);
}